// Round 1
// baseline (472.006 us; speedup 1.0000x reference)
//
#include <hip/hip_runtime.h>

#define NB    133
#define NBP   136            // gT f-row stride in shorts: 68 words = 4 mod 32 -> 2-way banks (free)
#define BATCH 256
#define HEADS 8
#define CDIM  128
#define DDIM  1024
#define MROWS (BATCH * NB)   // 34048 = 133*256
#define NDIM  (HEADS * CDIM)
#define BH    (BATCH * HEADS)
#define NT    32             // K tiles of BK=32

typedef __bf16 bf16_t;
typedef bf16_t bf16x8 __attribute__((ext_vector_type(8)));
typedef float  f32x4  __attribute__((ext_vector_type(4)));

__device__ __forceinline__ unsigned short f2bf(float f) {
  unsigned u = __float_as_uint(f);
  u += 0x7fffu + ((u >> 16) & 1u);
  return (unsigned short)(u >> 16);
}
__device__ __forceinline__ void load_lds16(const void* g, void* l) {
  __builtin_amdgcn_global_load_lds(
      (__attribute__((address_space(1))) void*)(g),
      (__attribute__((address_space(3))) void*)(l), 16, 0, 0);
}
__device__ __forceinline__ void bar() {
  asm volatile("" ::: "memory");
  __builtin_amdgcn_s_barrier();
  asm volatile("" ::: "memory");
}
#define VMWAIT(n) asm volatile("s_waitcnt vmcnt(" #n ")" ::: "memory")

// ---------------- fp32 -> bf16 convert, x and W in one launch ----------------
__global__ __launch_bounds__(256) void cvt_kernel(const float* __restrict__ x,
                                                  const float* __restrict__ W,
                                                  unsigned short* __restrict__ xb,
                                                  unsigned short* __restrict__ wb) {
  const int nx = MROWS * DDIM / 8, nw = NDIM * DDIM / 8;
  int i = blockIdx.x * 256 + threadIdx.x;
  const float* src; unsigned short* dst; int k;
  if (i < nx)           { src = x; dst = xb; k = i; }
  else if (i < nx + nw) { src = W; dst = wb; k = i - nx; }
  else return;
  const float4* s4 = (const float4*)src;
  float4 a = s4[(size_t)k * 2];
  float4 b = s4[(size_t)k * 2 + 1];
  union { unsigned short u[8]; uint4 v; } p;
  p.u[0] = f2bf(a.x); p.u[1] = f2bf(a.y); p.u[2] = f2bf(a.z); p.u[3] = f2bf(a.w);
  p.u[4] = f2bf(b.x); p.u[5] = f2bf(b.y); p.u[6] = f2bf(b.z); p.u[7] = f2bf(b.w);
  ((uint4*)dst)[k] = p.v;
}

// ---------------- adjacency bitmasks, one block per row/col ----------------
__global__ __launch_bounds__(192) void mask_kernel(const float* __restrict__ adj,
                                                   unsigned* __restrict__ rm,
                                                   unsigned* __restrict__ cm) {
  const int tid = threadIdx.x, lane = tid & 63, wv = tid >> 6, blk = blockIdx.x;
  if (blk < 144) {
    const int i = blk;
    bool on = (i < NB) && (tid < NB) && (adj[i * NB + tid] != 0.f);
    unsigned long long bb = __ballot(on);
    if (lane == 0)  rm[i * 6 + wv * 2]     = (unsigned)bb;
    if (lane == 32) rm[i * 6 + wv * 2 + 1] = (unsigned)(bb >> 32);
  } else {
    const int j = blk - 144;
    bool on = (tid < NB) && (adj[tid * NB + j] != 0.f);
    unsigned long long bb = __ballot(on);
    if (lane == 0)  cm[j * 6 + wv * 2]     = (unsigned)bb;
    if (lane == 32) cm[j * 6 + wv * 2 + 1] = (unsigned)(bb >> 32);
  }
}

// ---------------- GEMM: g = x @ W^T, fused si/sj ----------------
// 256x256 tile, 8 waves (2M x 4N), BK=32, 4-deep LDS ring, counted vmcnt(8),
// raw s_barrier (never drains vmem in the main loop), setprio around MFMA.
// Swizzle: LDS slot (row, s) holds global 16B-chunk s ^ ((row>>1)&3)
// (identical involution to the proven 128^2 kernel; 0 bank conflicts).
__global__ __launch_bounds__(512, 2) void gemm_kernel(const unsigned short* __restrict__ xb,
                                                      const unsigned short* __restrict__ wb,
                                                      const float* __restrict__ attn_w,
                                                      unsigned short* __restrict__ gb,
                                                      float* __restrict__ si_ws,
                                                      float* __restrict__ sj_ws) {
  __shared__ __attribute__((aligned(16))) unsigned short lds[4][2][8192]; // ring of 4: [buf][A/B][256*32]
  __shared__ float sred[2][8][128];

  const int tid = threadIdx.x;
  const int bn = blockIdx.x & 3, bm = blockIdx.x >> 2;  // 133 m-tiles x 4 n-tiles
  const int lane = tid & 63, w = tid >> 6;
  const int wr = w >> 2, wc = w & 3;                    // wave tile: rows wr*128, cols wc*64
  const int q = lane >> 4, li = lane & 15;
  const int sub = (q ^ ((li >> 1) & 3)) * 8;            // swizzled chunk slot for frag reads

  const unsigned short* Ab = xb + (size_t)bm * 256 * DDIM;
  const unsigned short* Bb = wb + (size_t)bn * 256 * DDIM;

  // staging: flat chunk u = tid + l*512; row=u>>2, lds slot=u&3, src chunk=(u&3)^((u>>3)&3)
  const int u0 = tid, u1 = tid + 512;
  const size_t sa0 = (size_t)(u0 >> 2) * DDIM + (((u0 & 3) ^ ((u0 >> 3) & 3)) * 8);
  const size_t sa1 = (size_t)(u1 >> 2) * DDIM + (((u1 & 3) ^ ((u1 >> 3) & 3)) * 8);

  f32x4 acc[8][4] = {};

#define STAGE(T) do { \
    unsigned short* _la = &lds[(T) & 3][0][0]; \
    unsigned short* _lb = &lds[(T) & 3][1][0]; \
    const int _k = (T) * 32; \
    load_lds16(Ab + sa0 + _k, _la + u0 * 8); \
    load_lds16(Ab + sa1 + _k, _la + u1 * 8); \
    load_lds16(Bb + sa0 + _k, _lb + u0 * 8); \
    load_lds16(Bb + sa1 + _k, _lb + u1 * 8); \
  } while (0)

#define COMPUTE(T) do { \
    const unsigned short* _as = &lds[(T) & 3][0][0]; \
    const unsigned short* _bs = &lds[(T) & 3][1][0]; \
    bf16x8 af[8], bfr[4]; \
    _Pragma("unroll") \
    for (int mi = 0; mi < 8; ++mi) \
      af[mi] = *(const bf16x8*)&_as[(wr * 128 + mi * 16 + li) * 32 + sub]; \
    _Pragma("unroll") \
    for (int ni = 0; ni < 4; ++ni) \
      bfr[ni] = *(const bf16x8*)&_bs[(wc * 64 + ni * 16 + li) * 32 + sub]; \
    __builtin_amdgcn_s_setprio(1); \
    _Pragma("unroll") \
    for (int mi = 0; mi < 8; ++mi) \
      _Pragma("unroll") \
      for (int ni = 0; ni < 4; ++ni) \
        acc[mi][ni] = __builtin_amdgcn_mfma_f32_16x16x32_bf16(af[mi], bfr[ni], acc[mi][ni], 0, 0, 0); \
    __builtin_amdgcn_s_setprio(0); \
  } while (0)

  // prologue: 3 tiles in flight (12 loads); wait tile0 (leave 8 outstanding)
  STAGE(0); STAGE(1); STAGE(2);
  VMWAIT(8);
  bar();
  // steady state: stage t+3 into the buffer tile t-1 vacated (guarded by the
  // iteration-(t-1) barrier); wait leaves tiles t+2,t+3 (8 loads) in flight.
  for (int t = 0; t < NT - 3; ++t) {
    STAGE(t + 3);
    COMPUTE(t);
    VMWAIT(8);
    bar();
  }
  COMPUTE(NT - 3); VMWAIT(4); bar();
  COMPUTE(NT - 2); VMWAIT(0); bar();
  COMPUTE(NT - 1);

  // ---- fused si/sj: per-head dot with wl/wr; head = bn*2 + (wc>>1) ----
  float wlv[4], wrv[4];
#pragma unroll
  for (int ni = 0; ni < 4; ++ni) {
    const int cc = (wc & 1) * 64 + ni * 16 + li;   // head-local column
    wlv[ni] = attn_w[cc];
    wrv[ni] = attn_w[CDIM + cc];
  }
#pragma unroll
  for (int mi = 0; mi < 8; ++mi)
#pragma unroll
    for (int rr = 0; rr < 4; ++rr) {
      float pj = 0.f, pi = 0.f;
#pragma unroll
      for (int ni = 0; ni < 4; ++ni) {
        pj += acc[mi][ni][rr] * wlv[ni];
        pi += acc[mi][ni][rr] * wrv[ni];
      }
#pragma unroll
      for (int d = 1; d < 16; d <<= 1) {
        pj += __shfl_xor(pj, d);
        pi += __shfl_xor(pi, d);
      }
      if (li == 0) {
        sred[0][w][mi * 16 + q * 4 + rr] = pj;
        sred[1][w][mi * 16 + q * 4 + rr] = pi;
      }
    }
  __syncthreads();
#pragma unroll
  for (int idx0 = 0; idx0 < 2; ++idx0) {
    const int idx = idx0 * 512 + tid;       // 1024 items: 2(which) x 2(hw) x 256(rows)
    const int row = idx & 255;
    const int hw = (idx >> 8) & 1;
    const int which = idx >> 9;
    const int wb2 = (row >> 7) * 4 + hw * 2;  // waves covering (row-half, head)
    const float v = sred[which][wb2][row & 127] + sred[which][wb2 + 1][row & 127];
    const int rg = bm * 256 + row;
    const int b = rg / NB, n = rg - b * NB;
    const int h = bn * 2 + hw;
    float* dst = which ? si_ws : sj_ws;
    dst[(b * HEADS + h) * NB + n] = v;
  }

  // ---- store g bf16, normal [row][col] layout ----
#pragma unroll
  for (int mi = 0; mi < 8; ++mi)
#pragma unroll
    for (int ni = 0; ni < 4; ++ni) {
      const int col = bn * 256 + wc * 64 + ni * 16 + li;
      const size_t row0 = (size_t)(bm * 256 + wr * 128 + mi * 16 + q * 4);
#pragma unroll
      for (int rr = 0; rr < 4; ++rr)
        gb[(row0 + rr) * NDIM + col] = f2bf(acc[mi][ni][rr]);
    }
#undef STAGE
#undef COMPUTE
}

// ---------------- column softmax stats: smrg[bh][j] = (sj_j, m_j + ln(denom_j)) ----------------
__global__ __launch_bounds__(192) void stats_kernel(const float* __restrict__ si_ws,
                                                    const float* __restrict__ sj_ws,
                                                    const unsigned* __restrict__ cm,
                                                    float2* __restrict__ smrg) {
  __shared__ float siL[NB];
  const int tid = threadIdx.x;
  const int base = blockIdx.x * NB;
  if (tid < NB) siL[tid] = si_ws[base + tid];
  __syncthreads();
  if (tid >= 160) return;
  float2 o = {0.f, 0.f};
  if (tid < NB) {
    const int j = tid;
    const float sjv = sj_ws[base + j];
    float m = -3.0e38f;
#pragma unroll
    for (int wd = 0; wd < 5; ++wd) {
      unsigned bits = cm[j * 6 + wd];
      while (bits) {
        const int i = __ffs(bits) - 1; bits &= bits - 1;
        float e = siL[wd * 32 + i] + sjv;
        e = e > 0.f ? e : 0.2f * e;
        m = fmaxf(m, e);
      }
    }
    float s = 0.f;
#pragma unroll
    for (int wd = 0; wd < 5; ++wd) {
      unsigned bits = cm[j * 6 + wd];
      while (bits) {
        const int i = __ffs(bits) - 1; bits &= bits - 1;
        float e = siL[wd * 32 + i] + sjv;
        e = e > 0.f ? e : 0.2f * e;
        s += __expf(e - m);
      }
    }
    o.x = sjv;
    o.y = m + __logf(s);   // weight = exp(e - o.y): rd folded into the exponent
  }
  smrg[(size_t)blockIdx.x * 160 + tid] = o;
}

// ---------------- aggregation: block = (b, h, f-half); LDS transpose of g ----------------
__global__ __launch_bounds__(256) void agg_kernel(const unsigned short* __restrict__ gb,
                                                  const float* __restrict__ si_ws,
                                                  const float2* __restrict__ smrg,
                                                  const unsigned* __restrict__ rm,
                                                  float* __restrict__ out) {
  __shared__ __attribute__((aligned(16))) unsigned short gTl[64 * NBP + 32]; // [f][j]
  __shared__ __attribute__((aligned(8))) float2 smrL[160];
  const int tid = threadIdx.x;
  const int bh = blockIdx.x >> 1, fh = blockIdx.x & 1;
  const int b = bh >> 3, h = bh & 7;
  const int base = bh * NB;

  // zero pad: cols 133..135 of every f-row + 32-short tail (MFMA K-overreads hit these)
  if (tid < 64) {
    gTl[tid * NBP + 133] = 0;
    *(unsigned*)&gTl[tid * NBP + 134] = 0;
  }
  if (tid >= 64 && tid < 80) *(unsigned*)&gTl[64 * NBP + 2 * (tid - 64)] = 0;
  if (tid < 160) smrL[tid] = smrg[(size_t)bh * 160 + tid];

  // coalesced read (16 lanes x 8B per j-row) + transpose via b16 LDS writes
  const unsigned short* gsrc = gb + (size_t)(b * NB) * NDIM + h * CDIM + fh * 64;
  for (int u = tid; u < NB * 16; u += 256) {
    const int j = u >> 4, fg = u & 15;
    const uint2 d = *(const uint2*)(gsrc + (size_t)j * NDIM + fg * 4);
    const int f0 = fg * 4;
    gTl[(f0 + 0) * NBP + j] = (unsigned short)(d.x);
    gTl[(f0 + 1) * NBP + j] = (unsigned short)(d.x >> 16);
    gTl[(f0 + 2) * NBP + j] = (unsigned short)(d.y);
    gTl[(f0 + 3) * NBP + j] = (unsigned short)(d.y >> 16);
  }
  __syncthreads();

  const int lane = tid & 63, wv = tid >> 6, q = lane >> 4, li = lane & 15;
  for (int mt = wv; mt < 9; mt += 4) {
    const int il = mt * 16 + li;
    const float si_r = si_ws[base + (il < NB ? il : NB - 1)];
    const unsigned* rmr = rm + il * 6;
    f32x4 acc[4] = {};
#pragma unroll
    for (int ks = 0; ks < 5; ++ks) {
      const int j0 = ks * 32 + q * 8;
      const unsigned bits = rmr[ks] >> (q * 8);
      bf16x8 afv;
#pragma unroll
      for (int jj = 0; jj < 8; ++jj) {
        const float2 sv = smrL[j0 + jj];
        float e = si_r + sv.x;
        e = e > 0.f ? e : 0.2f * e;
        const float wgt = ((bits >> jj) & 1u) ? __expf(e - sv.y) : 0.f;
        afv[jj] = (bf16_t)wgt;
      }
#pragma unroll
      for (int n = 0; n < 4; ++n) {
        const bf16x8 bv = *(const bf16x8*)&gTl[(n * 16 + li) * NBP + j0];
        acc[n] = __builtin_amdgcn_mfma_f32_16x16x32_bf16(afv, bv, acc[n], 0, 0, 0);
      }
    }
    float* obase = out + (size_t)(b * NB) * NDIM + h * CDIM + fh * 64;
#pragma unroll
    for (int n = 0; n < 4; ++n)
#pragma unroll
      for (int rr = 0; rr < 4; ++rr) {
        const int i = mt * 16 + q * 4 + rr;
        if (i < NB) obase[(size_t)i * NDIM + n * 16 + li] = acc[n][rr];
      }
  }
}

extern "C" void kernel_launch(void* const* d_in, const int* in_sizes, int n_in,
                              void* d_out, int out_size, void* d_ws, size_t ws_size,
                              hipStream_t stream) {
  const float* x      = (const float*)d_in[0];
  const float* W      = (const float*)d_in[1];
  const float* attn_w = (const float*)d_in[2];
  const float* adj    = (const float*)d_in[3];
  float* out = (float*)d_out;
  char* ws = (char*)d_ws;

  // workspace layout (bytes), ~143.7 MB; smrg overlays xb (xb dead after gemm)
  unsigned short* xb = (unsigned short*)(ws + 0);            // 69,730,304
  unsigned short* wb = (unsigned short*)(ws + 69730304);     //  2,097,152
  unsigned short* gb = (unsigned short*)(ws + 71827456);     // 69,730,304
  float* si = (float*)(ws + 141557760);                      //  1,089,536
  float* sj = (float*)(ws + 142647296);                      //  1,089,536
  unsigned* rm = (unsigned*)(ws + 143736832);                //      3,456
  unsigned* cm = (unsigned*)(ws + 143740288);                //      3,192
  float2* smrg = (float2*)(ws + 0);                          //  2,621,440 (overlay)

  const int ncvt = (MROWS * DDIM + NDIM * DDIM) / 8;
  cvt_kernel<<<(ncvt + 255) / 256, 256, 0, stream>>>(x, W, xb, wb);
  mask_kernel<<<277, 192, 0, stream>>>(adj, rm, cm);
  gemm_kernel<<<133 * 4, 512, 0, stream>>>(xb, wb, attn_w, gb, si, sj);
  stats_kernel<<<BH, 192, 0, stream>>>(si, sj, cm, smrg);
  agg_kernel<<<BH * 2, 256, 0, stream>>>(gb, si, smrg, rm, out);
}

// Round 2
// 445.109 us; speedup vs baseline: 1.0604x; 1.0604x over previous
//
#include <hip/hip_runtime.h>

#define NB    133
#define NBP   136            // gT f-row stride in shorts: 68 words = 4 mod 32 -> 2-way banks (free)
#define BATCH 256
#define HEADS 8
#define CDIM  128
#define DDIM  1024
#define MROWS (BATCH * NB)   // 34048 = 133*256
#define NDIM  (HEADS * CDIM)
#define BH    (BATCH * HEADS)
#define NKT   16             // K tiles of BK=64

typedef __bf16 bf16_t;
typedef bf16_t bf16x8 __attribute__((ext_vector_type(8)));
typedef float  f32x4  __attribute__((ext_vector_type(4)));

__device__ __forceinline__ unsigned short f2bf(float f) {
  unsigned u = __float_as_uint(f);
  u += 0x7fffu + ((u >> 16) & 1u);
  return (unsigned short)(u >> 16);
}
__device__ __forceinline__ void load_lds16(const void* g, void* l) {
  __builtin_amdgcn_global_load_lds(
      (__attribute__((address_space(1))) void*)(g),
      (__attribute__((address_space(3))) void*)(l), 16, 0, 0);
}
__device__ __forceinline__ void bar() {
  asm volatile("" ::: "memory");
  __builtin_amdgcn_s_barrier();
  asm volatile("" ::: "memory");
}
#define VMWAIT(n) asm volatile("s_waitcnt vmcnt(" #n ")" ::: "memory")

// ---------------- fp32 -> bf16 convert, x and W in one launch ----------------
__global__ __launch_bounds__(256) void cvt_kernel(const float* __restrict__ x,
                                                  const float* __restrict__ W,
                                                  unsigned short* __restrict__ xb,
                                                  unsigned short* __restrict__ wb) {
  const int nx = MROWS * DDIM / 8, nw = NDIM * DDIM / 8;
  int i = blockIdx.x * 256 + threadIdx.x;
  const float* src; unsigned short* dst; int k;
  if (i < nx)           { src = x; dst = xb; k = i; }
  else if (i < nx + nw) { src = W; dst = wb; k = i - nx; }
  else return;
  const float4* s4 = (const float4*)src;
  float4 a = s4[(size_t)k * 2];
  float4 b = s4[(size_t)k * 2 + 1];
  union { unsigned short u[8]; uint4 v; } p;
  p.u[0] = f2bf(a.x); p.u[1] = f2bf(a.y); p.u[2] = f2bf(a.z); p.u[3] = f2bf(a.w);
  p.u[4] = f2bf(b.x); p.u[5] = f2bf(b.y); p.u[6] = f2bf(b.z); p.u[7] = f2bf(b.w);
  ((uint4*)dst)[k] = p.v;
}

// ---------------- adjacency bitmasks, one block per row/col ----------------
__global__ __launch_bounds__(192) void mask_kernel(const float* __restrict__ adj,
                                                   unsigned* __restrict__ rm,
                                                   unsigned* __restrict__ cm) {
  const int tid = threadIdx.x, lane = tid & 63, wv = tid >> 6, blk = blockIdx.x;
  if (blk < 144) {
    const int i = blk;
    bool on = (i < NB) && (tid < NB) && (adj[i * NB + tid] != 0.f);
    unsigned long long bb = __ballot(on);
    if (lane == 0)  rm[i * 6 + wv * 2]     = (unsigned)bb;
    if (lane == 32) rm[i * 6 + wv * 2 + 1] = (unsigned)(bb >> 32);
  } else {
    const int j = blk - 144;
    bool on = (tid < NB) && (adj[tid * NB + j] != 0.f);
    unsigned long long bb = __ballot(on);
    if (lane == 0)  cm[j * 6 + wv * 2]     = (unsigned)bb;
    if (lane == 32) cm[j * 6 + wv * 2 + 1] = (unsigned)(bb >> 32);
  }
}

// ---------------- GEMM: g = x @ W^T, fused si/sj (m201 8-phase port) ----------------
// 256x256 tile, 8 waves (2Mx4N), BK=64, double-buffered LDS, 4 phases/K-tile,
// 2 barriers/phase, vmcnt(8) only at phase 4 (full tile prefetch in flight).
// Quadrant order (0,0)->(0,1)->(1,1)->(1,0): frag reads 12/4/8/0 per phase.
// Staging targets only LDS halves already fully consumed:
//   B halves free after P2's barrier -> staged in P3; A halves after P3 -> P4.
// Swizzle for 64-short rows: chunk slot = c ^ (row&7) -> 8 slot-groups x 8 lanes,
// conflict-free b128 reads; global_load_lds dest linear, source pre-swizzled.
__global__ __launch_bounds__(512, 2) void gemm_kernel(const unsigned short* __restrict__ xb,
                                                      const unsigned short* __restrict__ wb,
                                                      const float* __restrict__ attn_w,
                                                      unsigned short* __restrict__ gb,
                                                      float* __restrict__ si_ws,
                                                      float* __restrict__ sj_ws) {
  __shared__ __attribute__((aligned(16))) unsigned short lds[2][2][256 * 64]; // [buf][A/B][row*64]
  __shared__ float sred[2][8][128];

  const int tid = threadIdx.x;
  // bijective XCD swizzle, nwg=532=66*8+4: XCD gets contiguous wg chunk ->
  // the 4 bn-blocks sharing an A panel co-reside on one XCD's L2.
  const int orig = blockIdx.x;
  const int xcd = orig & 7, lo = orig >> 3;
  const int wg = (xcd < 4) ? (xcd * 67 + lo) : (268 + (xcd - 4) * 66 + lo);
  const int bn = wg & 3, bm = wg >> 2;

  const int lane = tid & 63, w = tid >> 6;
  const int wr = w >> 2, wc = w & 3;        // wave tile: rows wr*128, cols wc*64
  const int q = lane >> 4, li = lane & 15;

  const unsigned short* Ab = xb + (size_t)bm * 256 * DDIM;
  const unsigned short* Bb = wb + (size_t)bn * 256 * DDIM;

  // staging: flat chunk f = tid + i*512; row = f>>3, lds slot = f&7,
  // source chunk = slot ^ (row&7) (inverse of the read swizzle).
  int soff[4];
#pragma unroll
  for (int i = 0; i < 4; ++i) {
    const int f = tid + i * 512;
    const int row = f >> 3, slot = f & 7;
    soff[i] = row * DDIM + ((slot ^ (row & 7)) << 3);
  }
#define STG(gp_, buf_, kt_, h_) do { \
    load_lds16((gp_) + soff[(h_) * 2]     + (kt_) * 64, (buf_) + (tid + (h_) * 1024) * 8); \
    load_lds16((gp_) + soff[(h_) * 2 + 1] + (kt_) * 64, (buf_) + (tid + 512 + (h_) * 1024) * 8); \
  } while (0)

  // frag read addressing: slot = (s*4+q) ^ (li&7)
  const int sl0 = ((q ^ (li & 7)) << 3);
  const int sl1 = (((4 + q) ^ (li & 7)) << 3);
  const int arow = (wr * 128 + li) * 64;
  const int brow = (wc * 64 + li) * 64;

  f32x4 acc[2][2][4][2] = {};   // [mq][nq][mi][ni]
  bf16x8 a[4][2], b0f[2][2], b1f[2][2];

  // prologue: tiles 0 and 1 fully staged; wait tile0 (tile1's 8 loads in flight)
  {
    unsigned short* A0 = &lds[0][0][0]; unsigned short* B0 = &lds[0][1][0];
    unsigned short* A1 = &lds[1][0][0]; unsigned short* B1 = &lds[1][1][0];
    STG(Bb, B0, 0, 0); STG(Bb, B0, 0, 1); STG(Ab, A0, 0, 0); STG(Ab, A0, 0, 1);
    STG(Bb, B1, 1, 0); STG(Bb, B1, 1, 1); STG(Ab, A1, 1, 0); STG(Ab, A1, 1, 1);
  }
  VMWAIT(8);
  bar();

#define LDA(mq_) { _Pragma("unroll") for (int mi = 0; mi < 4; ++mi) { \
      const int r_ = arow + ((mq_) * 64 + mi * 16) * 64; \
      a[mi][0] = *(const bf16x8*)&as[r_ + sl0]; \
      a[mi][1] = *(const bf16x8*)&as[r_ + sl1]; } }
#define LDB(dst_, nq_) { _Pragma("unroll") for (int ni = 0; ni < 2; ++ni) { \
      const int r_ = brow + ((nq_) * 32 + ni * 16) * 64; \
      dst_[ni][0] = *(const bf16x8*)&bs[r_ + sl0]; \
      dst_[ni][1] = *(const bf16x8*)&bs[r_ + sl1]; } }
#define MM(mq_, nq_, bv_) { \
      __builtin_amdgcn_s_setprio(1); \
      _Pragma("unroll") for (int mi = 0; mi < 4; ++mi) \
      _Pragma("unroll") for (int ni = 0; ni < 2; ++ni) { \
        acc[mq_][nq_][mi][ni] = __builtin_amdgcn_mfma_f32_16x16x32_bf16(a[mi][0], bv_[ni][0], acc[mq_][nq_][mi][ni], 0, 0, 0); \
        acc[mq_][nq_][mi][ni] = __builtin_amdgcn_mfma_f32_16x16x32_bf16(a[mi][1], bv_[ni][1], acc[mq_][nq_][mi][ni], 0, 0, 0); } \
      __builtin_amdgcn_s_setprio(0); }

#pragma unroll 2
  for (int t = 0; t < NKT; ++t) {
    const unsigned short* as = &lds[t & 1][0][0];
    const unsigned short* bs = &lds[t & 1][1][0];
    unsigned short* asw = &lds[t & 1][0][0];   // tile t+2 shares parity with t
    unsigned short* bsw = &lds[t & 1][1][0];

    // P1: quad (0,0) — 12 frag reads
    LDA(0); LDB(b0f, 0);
    bar();
    MM(0, 0, b0f);
    bar();
    // P2: quad (0,1) — 4 frag reads (A reuse)
    LDB(b1f, 1);
    bar();
    MM(0, 1, b1f);
    bar();
    // P3: quad (1,1) — 8 frag reads; stage B(t+2) (B halves consumed by end of P2)
    LDA(1);
    if (t < NKT - 2) { STG(Bb, bsw, t + 2, 0); STG(Bb, bsw, t + 2, 1); }
    bar();
    MM(1, 1, b1f);
    bar();
    // P4: quad (1,0) — 0 frag reads; stage A(t+2) (A halves consumed by end of P3);
    // counted wait: drain tile t+1's 8 loads, leave tile t+2's 8 in flight.
    if (t < NKT - 2) {
      STG(Ab, asw, t + 2, 0); STG(Ab, asw, t + 2, 1);
      VMWAIT(8);
    } else {
      VMWAIT(0);
    }
    bar();
    MM(1, 0, b0f);
    bar();
  }
#undef LDA
#undef LDB
#undef MM
#undef STG

#define ACC(m8, n4) acc[(m8) >> 2][(n4) >> 1][(m8) & 3][(n4) & 1]

  // ---- fused si/sj: per-head dot with wl/wr; head = bn*2 + (wc>>1) ----
  float wlv[4], wrv[4];
#pragma unroll
  for (int n4 = 0; n4 < 4; ++n4) {
    const int cc = (wc & 1) * 64 + n4 * 16 + li;   // head-local column
    wlv[n4] = attn_w[cc];
    wrv[n4] = attn_w[CDIM + cc];
  }
#pragma unroll
  for (int m8 = 0; m8 < 8; ++m8)
#pragma unroll
    for (int rr = 0; rr < 4; ++rr) {
      float pj = 0.f, pi = 0.f;
#pragma unroll
      for (int n4 = 0; n4 < 4; ++n4) {
        pj += ACC(m8, n4)[rr] * wlv[n4];
        pi += ACC(m8, n4)[rr] * wrv[n4];
      }
#pragma unroll
      for (int d = 1; d < 16; d <<= 1) {
        pj += __shfl_xor(pj, d);
        pi += __shfl_xor(pi, d);
      }
      if (li == 0) {
        sred[0][w][m8 * 16 + q * 4 + rr] = pj;
        sred[1][w][m8 * 16 + q * 4 + rr] = pi;
      }
    }
  __syncthreads();
#pragma unroll
  for (int idx0 = 0; idx0 < 2; ++idx0) {
    const int idx = idx0 * 512 + tid;       // 1024 items: 2(which) x 2(hw) x 256(rows)
    const int row = idx & 255;
    const int hw = (idx >> 8) & 1;
    const int which = idx >> 9;
    const int wb2 = (row >> 7) * 4 + hw * 2;  // waves covering (row-half, head)
    const float v = sred[which][wb2][row & 127] + sred[which][wb2 + 1][row & 127];
    const int rg = bm * 256 + row;
    const int b = rg / NB, n = rg - b * NB;
    const int h = bn * 2 + hw;
    float* dst = which ? si_ws : sj_ws;
    dst[(b * HEADS + h) * NB + n] = v;
  }

  // ---- store g bf16, normal [row][col] layout ----
#pragma unroll
  for (int m8 = 0; m8 < 8; ++m8)
#pragma unroll
    for (int n4 = 0; n4 < 4; ++n4) {
      const int col = bn * 256 + wc * 64 + n4 * 16 + li;
      const size_t row0 = (size_t)(bm * 256 + wr * 128 + m8 * 16 + q * 4);
#pragma unroll
      for (int rr = 0; rr < 4; ++rr)
        gb[(row0 + rr) * NDIM + col] = f2bf(ACC(m8, n4)[rr]);
    }
#undef ACC
}

// ---------------- column softmax stats: smrg[bh][j] = (sj_j, m_j + ln(denom_j)) ----------------
__global__ __launch_bounds__(192) void stats_kernel(const float* __restrict__ si_ws,
                                                    const float* __restrict__ sj_ws,
                                                    const unsigned* __restrict__ cm,
                                                    float2* __restrict__ smrg) {
  __shared__ float siL[NB];
  const int tid = threadIdx.x;
  const int base = blockIdx.x * NB;
  if (tid < NB) siL[tid] = si_ws[base + tid];
  __syncthreads();
  if (tid >= 160) return;
  float2 o = {0.f, 0.f};
  if (tid < NB) {
    const int j = tid;
    const float sjv = sj_ws[base + j];
    float m = -3.0e38f;
#pragma unroll
    for (int wd = 0; wd < 5; ++wd) {
      unsigned bits = cm[j * 6 + wd];
      while (bits) {
        const int i = __ffs(bits) - 1; bits &= bits - 1;
        float e = siL[wd * 32 + i] + sjv;
        e = e > 0.f ? e : 0.2f * e;
        m = fmaxf(m, e);
      }
    }
    float s = 0.f;
#pragma unroll
    for (int wd = 0; wd < 5; ++wd) {
      unsigned bits = cm[j * 6 + wd];
      while (bits) {
        const int i = __ffs(bits) - 1; bits &= bits - 1;
        float e = siL[wd * 32 + i] + sjv;
        e = e > 0.f ? e : 0.2f * e;
        s += __expf(e - m);
      }
    }
    o.x = sjv;
    o.y = m + __logf(s);   // weight = exp(e - o.y): rd folded into the exponent
  }
  smrg[(size_t)blockIdx.x * 160 + tid] = o;
}

// ---------------- aggregation: block = (b, h, f-half); LDS transpose of g ----------------
__global__ __launch_bounds__(256) void agg_kernel(const unsigned short* __restrict__ gb,
                                                  const float* __restrict__ si_ws,
                                                  const float2* __restrict__ smrg,
                                                  const unsigned* __restrict__ rm,
                                                  float* __restrict__ out) {
  __shared__ __attribute__((aligned(16))) unsigned short gTl[64 * NBP + 32]; // [f][j]
  __shared__ __attribute__((aligned(8))) float2 smrL[160];
  const int tid = threadIdx.x;
  const int bh = blockIdx.x >> 1, fh = blockIdx.x & 1;
  const int b = bh >> 3, h = bh & 7;
  const int base = bh * NB;

  // zero pad: cols 133..135 of every f-row + 32-short tail (MFMA K-overreads hit these)
  if (tid < 64) {
    gTl[tid * NBP + 133] = 0;
    *(unsigned*)&gTl[tid * NBP + 134] = 0;
  }
  if (tid >= 64 && tid < 80) *(unsigned*)&gTl[64 * NBP + 2 * (tid - 64)] = 0;
  if (tid < 160) smrL[tid] = smrg[(size_t)bh * 160 + tid];

  // coalesced read (16 lanes x 8B per j-row) + transpose via b16 LDS writes
  const unsigned short* gsrc = gb + (size_t)(b * NB) * NDIM + h * CDIM + fh * 64;
  for (int u = tid; u < NB * 16; u += 256) {
    const int j = u >> 4, fg = u & 15;
    const uint2 d = *(const uint2*)(gsrc + (size_t)j * NDIM + fg * 4);
    const int f0 = fg * 4;
    gTl[(f0 + 0) * NBP + j] = (unsigned short)(d.x);
    gTl[(f0 + 1) * NBP + j] = (unsigned short)(d.x >> 16);
    gTl[(f0 + 2) * NBP + j] = (unsigned short)(d.y);
    gTl[(f0 + 3) * NBP + j] = (unsigned short)(d.y >> 16);
  }
  __syncthreads();

  const int lane = tid & 63, wv = tid >> 6, q = lane >> 4, li = lane & 15;
  for (int mt = wv; mt < 9; mt += 4) {
    const int il = mt * 16 + li;
    const float si_r = si_ws[base + (il < NB ? il : NB - 1)];
    const unsigned* rmr = rm + il * 6;
    f32x4 acc[4] = {};
#pragma unroll
    for (int ks = 0; ks < 5; ++ks) {
      const int j0 = ks * 32 + q * 8;
      const unsigned bits = rmr[ks] >> (q * 8);
      bf16x8 afv;
#pragma unroll
      for (int jj = 0; jj < 8; ++jj) {
        const float2 sv = smrL[j0 + jj];
        float e = si_r + sv.x;
        e = e > 0.f ? e : 0.2f * e;
        const float wgt = ((bits >> jj) & 1u) ? __expf(e - sv.y) : 0.f;
        afv[jj] = (bf16_t)wgt;
      }
#pragma unroll
      for (int n = 0; n < 4; ++n) {
        const bf16x8 bv = *(const bf16x8*)&gTl[(n * 16 + li) * NBP + j0];
        acc[n] = __builtin_amdgcn_mfma_f32_16x16x32_bf16(afv, bv, acc[n], 0, 0, 0);
      }
    }
    float* obase = out + (size_t)(b * NB) * NDIM + h * CDIM + fh * 64;
#pragma unroll
    for (int n = 0; n < 4; ++n)
#pragma unroll
      for (int rr = 0; rr < 4; ++rr) {
        const int i = mt * 16 + q * 4 + rr;
        if (i < NB) obase[(size_t)i * NDIM + n * 16 + li] = acc[n][rr];
      }
  }
}

extern "C" void kernel_launch(void* const* d_in, const int* in_sizes, int n_in,
                              void* d_out, int out_size, void* d_ws, size_t ws_size,
                              hipStream_t stream) {
  const float* x      = (const float*)d_in[0];
  const float* W      = (const float*)d_in[1];
  const float* attn_w = (const float*)d_in[2];
  const float* adj    = (const float*)d_in[3];
  float* out = (float*)d_out;
  char* ws = (char*)d_ws;

  // workspace layout (bytes), ~143.7 MB; smrg overlays xb (xb dead after gemm)
  unsigned short* xb = (unsigned short*)(ws + 0);            // 69,730,304
  unsigned short* wb = (unsigned short*)(ws + 69730304);     //  2,097,152
  unsigned short* gb = (unsigned short*)(ws + 71827456);     // 69,730,304
  float* si = (float*)(ws + 141557760);                      //  1,089,536
  float* sj = (float*)(ws + 142647296);                      //  1,089,536
  unsigned* rm = (unsigned*)(ws + 143736832);                //      3,456
  unsigned* cm = (unsigned*)(ws + 143740288);                //      3,192
  float2* smrg = (float2*)(ws + 0);                          //  2,621,440 (overlay)

  const int ncvt = (MROWS * DDIM + NDIM * DDIM) / 8;
  cvt_kernel<<<(ncvt + 255) / 256, 256, 0, stream>>>(x, W, xb, wb);
  mask_kernel<<<277, 192, 0, stream>>>(adj, rm, cm);
  gemm_kernel<<<133 * 4, 512, 0, stream>>>(xb, wb, attn_w, gb, si, sj);
  stats_kernel<<<BH, 192, 0, stream>>>(si, sj, cm, smrg);
  agg_kernel<<<BH * 2, 256, 0, stream>>>(gb, si, smrg, rm, out);
}

// Round 4
// 437.253 us; speedup vs baseline: 1.0795x; 1.0180x over previous
//
#include <hip/hip_runtime.h>

#define NB    133
#define NBP   136            // gT f-row stride in shorts: 68 words = 4 mod 32 -> 2-way banks (free)
#define BATCH 256
#define HEADS 8
#define CDIM  128
#define DDIM  1024
#define MROWS (BATCH * NB)   // 34048 = 266*128
#define NDIM  (HEADS * CDIM)
#define BH    (BATCH * HEADS)
#define NKT   32             // K tiles of BK=32

typedef __bf16 bf16_t;
typedef bf16_t bf16x8 __attribute__((ext_vector_type(8)));
typedef float  f32x4  __attribute__((ext_vector_type(4)));

__device__ __forceinline__ unsigned short f2bf(float f) {
  unsigned u = __float_as_uint(f);
  u += 0x7fffu + ((u >> 16) & 1u);
  return (unsigned short)(u >> 16);
}
__device__ __forceinline__ void load_lds16(const void* g, void* l) {
  __builtin_amdgcn_global_load_lds(
      (__attribute__((address_space(1))) void*)(g),
      (__attribute__((address_space(3))) void*)(l), 16, 0, 0);
}
__device__ __forceinline__ void bar() {
  asm volatile("" ::: "memory");
  __builtin_amdgcn_s_barrier();
  asm volatile("" ::: "memory");
}
#define VMWAIT(n) asm volatile("s_waitcnt vmcnt(" #n ")" ::: "memory")

// ---------------- fp32 -> bf16 convert, x and W in one launch ----------------
__global__ __launch_bounds__(256) void cvt_kernel(const float* __restrict__ x,
                                                  const float* __restrict__ W,
                                                  unsigned short* __restrict__ xb,
                                                  unsigned short* __restrict__ wb) {
  const int nx = MROWS * DDIM / 8, nw = NDIM * DDIM / 8;
  int i = blockIdx.x * 256 + threadIdx.x;
  const float* src; unsigned short* dst; int k;
  if (i < nx)           { src = x; dst = xb; k = i; }
  else if (i < nx + nw) { src = W; dst = wb; k = i - nx; }
  else return;
  const float4* s4 = (const float4*)src;
  float4 a = s4[(size_t)k * 2];
  float4 b = s4[(size_t)k * 2 + 1];
  union { unsigned short u[8]; uint4 v; } p;
  p.u[0] = f2bf(a.x); p.u[1] = f2bf(a.y); p.u[2] = f2bf(a.z); p.u[3] = f2bf(a.w);
  p.u[4] = f2bf(b.x); p.u[5] = f2bf(b.y); p.u[6] = f2bf(b.z); p.u[7] = f2bf(b.w);
  ((uint4*)dst)[k] = p.v;
}

// ---------------- adjacency bitmasks, one block per row/col ----------------
__global__ __launch_bounds__(192) void mask_kernel(const float* __restrict__ adj,
                                                   unsigned* __restrict__ rm,
                                                   unsigned* __restrict__ cm) {
  const int tid = threadIdx.x, lane = tid & 63, wv = tid >> 6, blk = blockIdx.x;
  if (blk < 144) {
    const int i = blk;
    bool on = (i < NB) && (tid < NB) && (adj[i * NB + tid] != 0.f);
    unsigned long long bb = __ballot(on);
    if (lane == 0)  rm[i * 6 + wv * 2]     = (unsigned)bb;
    if (lane == 32) rm[i * 6 + wv * 2 + 1] = (unsigned)(bb >> 32);
  } else {
    const int j = blk - 144;
    bool on = (tid < NB) && (adj[tid * NB + j] != 0.f);
    unsigned long long bb = __ballot(on);
    if (lane == 0)  cm[j * 6 + wv * 2]     = (unsigned)bb;
    if (lane == 32) cm[j * 6 + wv * 2 + 1] = (unsigned)(bb >> 32);
  }
}

// ---------------- GEMM: g = x @ W^T, fused si/sj ----------------
// M128 x N256 tile, 256 threads (4 waves, 1M x 4N), wave tile 128x64, BK=32.
// RING OF 3 LDS buffers (76 KiB total) -> 2 blocks/CU. Grid 266*4 = 1064 = 8*133.
// 2 phases/K-tile: P1{LDA 8 + LDB01 2; bar; 16 MFMA} P2{LDB23 2 + stage(t+2) 6;
// vmcnt(6); bar; 16 MFMA}. Stage targets buf[(t+2)%3] = the buffer tile t-1
// read: every wave's reads of it COMPLETED before it reached bar#1 of iter t
// (lgkm wait precedes its iter-(t-1) MFMA set 2), and the STG issues after
// bar#1 of iter t -> WAR-safe by barrier separation (the R3 intra-phase
// same-buffer race is gone). Counted vmcnt never drains in the main loop.
// Swizzle (32-short rows, 4 chunks): LDS slot s holds chunk s ^ (row&3);
// frag read slot = q ^ (li&3) -> 2 lanes/bank (free), 16B aligned.
__global__ __launch_bounds__(256, 2) void gemm_kernel(const unsigned short* __restrict__ xb,
                                                      const unsigned short* __restrict__ wb,
                                                      const float* __restrict__ attn_w,
                                                      unsigned short* __restrict__ gb,
                                                      float* __restrict__ si_ws,
                                                      float* __restrict__ sj_ws) {
  __shared__ __attribute__((aligned(16))) unsigned short Abuf[3][128 * 32];
  __shared__ __attribute__((aligned(16))) unsigned short Bbuf[3][256 * 32];
  __shared__ float sred[2][4][128];

  const int tid = threadIdx.x;
  // bijective XCD swizzle: nwg = 1064 = 8*133 exactly.
  const int orig = blockIdx.x;
  const int wg = (orig & 7) * 133 + (orig >> 3);
  const int bn = wg & 3, bm = wg >> 2;            // 266 m-tiles x 4 n-tiles

  const int lane = tid & 63, w = tid >> 6;        // wave w: cols w*64, rows 0..127
  const int q = lane >> 4, li = lane & 15;

  const unsigned short* Ab = xb + (size_t)bm * 128 * DDIM;
  const unsigned short* Bb = wb + (size_t)bn * 256 * DDIM;

  // staging: flat chunk f = tid + i*256; row = f>>2, lds slot = f&3,
  // source chunk = slot ^ (row&3) (inverse of read swizzle).
  int sA[2], sB[4];
#pragma unroll
  for (int i = 0; i < 2; ++i) {
    const int f = tid + i * 256;
    sA[i] = (f >> 2) * DDIM + (((f & 3) ^ ((f >> 2) & 3)) << 3);
  }
#pragma unroll
  for (int i = 0; i < 4; ++i) {
    const int f = tid + i * 256;
    sB[i] = (f >> 2) * DDIM + (((f & 3) ^ ((f >> 2) & 3)) << 3);
  }
#define STGA(buf_, kt_) do { \
    load_lds16(Ab + sA[0] + (kt_) * 32, &Abuf[buf_][tid * 8]); \
    load_lds16(Ab + sA[1] + (kt_) * 32, &Abuf[buf_][(tid + 256) * 8]); \
  } while (0)
#define STGB(buf_, kt_) do { \
    load_lds16(Bb + sB[0] + (kt_) * 32, &Bbuf[buf_][tid * 8]); \
    load_lds16(Bb + sB[1] + (kt_) * 32, &Bbuf[buf_][(tid + 256) * 8]); \
    load_lds16(Bb + sB[2] + (kt_) * 32, &Bbuf[buf_][(tid + 512) * 8]); \
    load_lds16(Bb + sB[3] + (kt_) * 32, &Bbuf[buf_][(tid + 768) * 8]); \
  } while (0)

  // frag reads: slot = q ^ (li&3) (row&3 == li&3 since 16 | frag row stride)
  const int asl = (q ^ (li & 3)) << 3;

  f32x4 acc[8][4] = {};
  bf16x8 a[8], bf01[2], bf23[2];

  // prologue: tiles 0,1 staged (12 loads); wait tile0 (tile1's 6 in flight)
  STGA(0, 0); STGB(0, 0);
  STGA(1, 1); STGB(1, 1);
  VMWAIT(6);
  bar();

  for (int t = 0; t < NKT; ++t) {
    const int cur = t % 3, nxt = (t + 2) % 3;
    const unsigned short* As = &Abuf[cur][0];
    const unsigned short* Bs = &Bbuf[cur][0];
    // P1: A frags (8) + B frags ni 0,1 (2)
#pragma unroll
    for (int mi = 0; mi < 8; ++mi)
      a[mi] = *(const bf16x8*)&As[(mi * 16 + li) * 32 + asl];
#pragma unroll
    for (int ni = 0; ni < 2; ++ni)
      bf01[ni] = *(const bf16x8*)&Bs[(w * 64 + ni * 16 + li) * 32 + asl];
    bar();
    __builtin_amdgcn_s_setprio(1);
#pragma unroll
    for (int mi = 0; mi < 8; ++mi)
#pragma unroll
      for (int ni = 0; ni < 2; ++ni)
        acc[mi][ni] = __builtin_amdgcn_mfma_f32_16x16x32_bf16(a[mi], bf01[ni], acc[mi][ni], 0, 0, 0);
    __builtin_amdgcn_s_setprio(0);
    // P2: B frags ni 2,3 (2) + stage tile t+2 into ring slot (t+2)%3 (the
    // buffer tile t-1 consumed; WAR-safe per header comment); counted wait
    // drains tile t+1's 6 loads, leaves t+2's 6 in flight.
#pragma unroll
    for (int ni = 0; ni < 2; ++ni)
      bf23[ni] = *(const bf16x8*)&Bs[(w * 64 + (ni + 2) * 16 + li) * 32 + asl];
    if (t < NKT - 2) {
      STGA(nxt, t + 2); STGB(nxt, t + 2);
      VMWAIT(6);
    } else {
      VMWAIT(0);
    }
    bar();
    __builtin_amdgcn_s_setprio(1);
#pragma unroll
    for (int mi = 0; mi < 8; ++mi)
#pragma unroll
      for (int ni = 0; ni < 2; ++ni)
        acc[mi][ni + 2] = __builtin_amdgcn_mfma_f32_16x16x32_bf16(a[mi], bf23[ni], acc[mi][ni + 2], 0, 0, 0);
    __builtin_amdgcn_s_setprio(0);
  }
#undef STGA
#undef STGB

  // ---- fused si/sj: per-head dot with wl/wr; head = bn*2 + (w>>1) ----
  float wlv[4], wrv[4];
#pragma unroll
  for (int ni = 0; ni < 4; ++ni) {
    const int cc = (w & 1) * 64 + ni * 16 + li;   // head-local column
    wlv[ni] = attn_w[cc];
    wrv[ni] = attn_w[CDIM + cc];
  }
#pragma unroll
  for (int mi = 0; mi < 8; ++mi)
#pragma unroll
    for (int rr = 0; rr < 4; ++rr) {
      float pj = 0.f, pi = 0.f;
#pragma unroll
      for (int ni = 0; ni < 4; ++ni) {
        pj += acc[mi][ni][rr] * wlv[ni];
        pi += acc[mi][ni][rr] * wrv[ni];
      }
#pragma unroll
      for (int d = 1; d < 16; d <<= 1) {
        pj += __shfl_xor(pj, d);
        pi += __shfl_xor(pi, d);
      }
      if (li == 0) {
        sred[0][w][mi * 16 + q * 4 + rr] = pj;
        sred[1][w][mi * 16 + q * 4 + rr] = pi;
      }
    }
  __syncthreads();
#pragma unroll
  for (int idx0 = 0; idx0 < 2; ++idx0) {
    const int idx = idx0 * 256 + tid;     // 512 items: 2(which) x 2(hw) x 128(rows)
    const int row = idx & 127;
    const int hw = (idx >> 7) & 1;
    const int which = idx >> 8;
    const float v = sred[which][hw * 2][row] + sred[which][hw * 2 + 1][row];
    const int rg = bm * 128 + row;
    const int b = rg / NB, n = rg - b * NB;
    const int h = bn * 2 + hw;
    float* dst = which ? si_ws : sj_ws;
    dst[(b * HEADS + h) * NB + n] = v;
  }

  // ---- store g bf16, normal [row][col] layout ----
#pragma unroll
  for (int mi = 0; mi < 8; ++mi)
#pragma unroll
    for (int ni = 0; ni < 4; ++ni) {
      const int col = bn * 256 + w * 64 + ni * 16 + li;
      const size_t row0 = (size_t)(bm * 128 + mi * 16 + q * 4);
#pragma unroll
      for (int rr = 0; rr < 4; ++rr)
        gb[(row0 + rr) * NDIM + col] = f2bf(acc[mi][ni][rr]);
    }
}

// ---------------- column softmax stats: smrg[bh][j] = (sj_j, m_j + ln(denom_j)) ----------------
__global__ __launch_bounds__(192) void stats_kernel(const float* __restrict__ si_ws,
                                                    const float* __restrict__ sj_ws,
                                                    const unsigned* __restrict__ cm,
                                                    float2* __restrict__ smrg) {
  __shared__ float siL[NB];
  const int tid = threadIdx.x;
  const int base = blockIdx.x * NB;
  if (tid < NB) siL[tid] = si_ws[base + tid];
  __syncthreads();
  if (tid >= 160) return;
  float2 o = {0.f, 0.f};
  if (tid < NB) {
    const int j = tid;
    const float sjv = sj_ws[base + j];
    float m = -3.0e38f;
#pragma unroll
    for (int wd = 0; wd < 5; ++wd) {
      unsigned bits = cm[j * 6 + wd];
      while (bits) {
        const int i = __ffs(bits) - 1; bits &= bits - 1;
        float e = siL[wd * 32 + i] + sjv;
        e = e > 0.f ? e : 0.2f * e;
        m = fmaxf(m, e);
      }
    }
    float s = 0.f;
#pragma unroll
    for (int wd = 0; wd < 5; ++wd) {
      unsigned bits = cm[j * 6 + wd];
      while (bits) {
        const int i = __ffs(bits) - 1; bits &= bits - 1;
        float e = siL[wd * 32 + i] + sjv;
        e = e > 0.f ? e : 0.2f * e;
        s += __expf(e - m);
      }
    }
    o.x = sjv;
    o.y = m + __logf(s);   // weight = exp(e - o.y): rd folded into the exponent
  }
  smrg[(size_t)blockIdx.x * 160 + tid] = o;
}

// ---------------- aggregation: block = (b, h, f-half); LDS transpose of g ----------------
__global__ __launch_bounds__(256) void agg_kernel(const unsigned short* __restrict__ gb,
                                                  const float* __restrict__ si_ws,
                                                  const float2* __restrict__ smrg,
                                                  const unsigned* __restrict__ rm,
                                                  float* __restrict__ out) {
  __shared__ __attribute__((aligned(16))) unsigned short gTl[64 * NBP + 32]; // [f][j]
  __shared__ __attribute__((aligned(8))) float2 smrL[160];
  const int tid = threadIdx.x;
  const int bh = blockIdx.x >> 1, fh = blockIdx.x & 1;
  const int b = bh >> 3, h = bh & 7;
  const int base = bh * NB;

  // zero pad: cols 133..135 of every f-row + 32-short tail (MFMA K-overreads hit these)
  if (tid < 64) {
    gTl[tid * NBP + 133] = 0;
    *(unsigned*)&gTl[tid * NBP + 134] = 0;
  }
  if (tid >= 64 && tid < 80) *(unsigned*)&gTl[64 * NBP + 2 * (tid - 64)] = 0;
  if (tid < 160) smrL[tid] = smrg[(size_t)bh * 160 + tid];

  // coalesced read (16 lanes x 8B per j-row) + transpose via b16 LDS writes
  const unsigned short* gsrc = gb + (size_t)(b * NB) * NDIM + h * CDIM + fh * 64;
  for (int u = tid; u < NB * 16; u += 256) {
    const int j = u >> 4, fg = u & 15;
    const uint2 d = *(const uint2*)(gsrc + (size_t)j * NDIM + fg * 4);
    const int f0 = fg * 4;
    gTl[(f0 + 0) * NBP + j] = (unsigned short)(d.x);
    gTl[(f0 + 1) * NBP + j] = (unsigned short)(d.x >> 16);
    gTl[(f0 + 2) * NBP + j] = (unsigned short)(d.y);
    gTl[(f0 + 3) * NBP + j] = (unsigned short)(d.y >> 16);
  }
  __syncthreads();

  const int lane = tid & 63, wv = tid >> 6, q = lane >> 4, li = lane & 15;
  for (int mt = wv; mt < 9; mt += 4) {
    const int il = mt * 16 + li;
    const float si_r = si_ws[base + (il < NB ? il : NB - 1)];
    const unsigned* rmr = rm + il * 6;
    f32x4 acc[4] = {};
#pragma unroll
    for (int ks = 0; ks < 5; ++ks) {
      const int j0 = ks * 32 + q * 8;
      const unsigned bits = rmr[ks] >> (q * 8);
      bf16x8 afv;
#pragma unroll
      for (int jj = 0; jj < 8; ++jj) {
        const float2 sv = smrL[j0 + jj];
        float e = si_r + sv.x;
        e = e > 0.f ? e : 0.2f * e;
        const float wgt = ((bits >> jj) & 1u) ? __expf(e - sv.y) : 0.f;
        afv[jj] = (bf16_t)wgt;
      }
#pragma unroll
      for (int n = 0; n < 4; ++n) {
        const bf16x8 bv = *(const bf16x8*)&gTl[(n * 16 + li) * NBP + j0];
        acc[n] = __builtin_amdgcn_mfma_f32_16x16x32_bf16(afv, bv, acc[n], 0, 0, 0);
      }
    }
    float* obase = out + (size_t)(b * NB) * NDIM + h * CDIM + fh * 64;
#pragma unroll
    for (int n = 0; n < 4; ++n)
#pragma unroll
      for (int rr = 0; rr < 4; ++rr) {
        const int i = mt * 16 + q * 4 + rr;
        if (i < NB) obase[(size_t)i * NDIM + n * 16 + li] = acc[n][rr];
      }
  }
}

extern "C" void kernel_launch(void* const* d_in, const int* in_sizes, int n_in,
                              void* d_out, int out_size, void* d_ws, size_t ws_size,
                              hipStream_t stream) {
  const float* x      = (const float*)d_in[0];
  const float* W      = (const float*)d_in[1];
  const float* attn_w = (const float*)d_in[2];
  const float* adj    = (const float*)d_in[3];
  float* out = (float*)d_out;
  char* ws = (char*)d_ws;

  // workspace layout (bytes), ~143.7 MB; smrg overlays xb (xb dead after gemm)
  unsigned short* xb = (unsigned short*)(ws + 0);            // 69,730,304
  unsigned short* wb = (unsigned short*)(ws + 69730304);     //  2,097,152
  unsigned short* gb = (unsigned short*)(ws + 71827456);     // 69,730,304
  float* si = (float*)(ws + 141557760);                      //  1,089,536
  float* sj = (float*)(ws + 142647296);                      //  1,089,536
  unsigned* rm = (unsigned*)(ws + 143736832);                //      3,456
  unsigned* cm = (unsigned*)(ws + 143740288);                //      3,192
  float2* smrg = (float2*)(ws + 0);                          //  2,621,440 (overlay)

  const int ncvt = (MROWS * DDIM + NDIM * DDIM) / 8;
  cvt_kernel<<<(ncvt + 255) / 256, 256, 0, stream>>>(x, W, xb, wb);
  mask_kernel<<<277, 192, 0, stream>>>(adj, rm, cm);
  gemm_kernel<<<266 * 4, 256, 0, stream>>>(xb, wb, attn_w, gb, si, sj);
  stats_kernel<<<BH, 192, 0, stream>>>(si, sj, cm, smrg);
  agg_kernel<<<BH * 2, 256, 0, stream>>>(gb, si, smrg, rm, out);
}